// Round 9
// baseline (172.356 us; speedup 1.0000x reference)
//
#include <hip/hip_runtime.h>

#define NN   512
#define NN2  (NN * NN)
#define BB   64
#define ITERS 10
#define WM   68                    // landing-window dim & stride
#define WWIN (WM * WM)             // 4624 floats
#define CAND (WM * 6)              // 408 candidate receiver cells per batch
#define SCH  8                     // s-chunks per candidate
#define CBLK 13                    // blocks per batch (13*256 = 3328 >= 408*8)

// redistribution region: window (68) + 12 halo each side
#define RD   92
#define RDU  23                    // RD/4 float4-units per row
#define RUNITS (RD * RDU)          // 2116
#define RST  97                    // LDS row stride (odd -> bank spread)
#define RTPB 1024

__device__ __forceinline__ float sigf(float x) { return 1.0f / (1.0f + __expf(-x)); }

__device__ __forceinline__ float maskf(float s, float t, float L) {
    if (fabsf(t) > 30.f || s < -30.f || s > L + 30.f) return 0.f;
    return sigf(3.f - fabsf(t)) * sigf(s) * sigf(L - s);
}

// base (pushed density without landing mass). s>=L or degenerate => self-splat => rho.
__device__ __forceinline__ float base_elem(float o, int gi, int gj,
        float p0x, float p0y, float pu0, float pu1, float L, bool degen) {
    float rx = (float)gi - p0x, ry = (float)gj - p0y;
    float s = rx * pu0 + ry * pu1;
    float t = -rx * pu1 + ry * pu0;
    float m = maskf(s, t, L);
    return (degen || s >= L) ? o : o * (1.f - m);
}

// ---------------- Pass 1: GATHER splat — no atomics, no LDS ----------------
// Receiving cells lie within 2 of the landing line (p1 + t*n): 68x6 candidates.
// For candidate c, sources have |t - t_c| <= |u0|+|u1| (hat weight self-gates),
// a strip parallel to u enumerated per band-major line as a 6-cell window
// around an affine center. All gating is exact per-cell; enumeration is a
// provable superset, so slop only costs work, never correctness.
__global__ void __launch_bounds__(256) splat_kernel(
        const float* __restrict__ occ,
        const float* __restrict__ as_,
        const float* __restrict__ ae_,
        float* __restrict__ ws) {
    const int bid = blockIdx.x;
    const int b   = bid / CBLK;
    const int blk = bid - b * CBLK;
    const int u   = blk * 256 + (int)threadIdx.x;   // 0..3327
    const int cc  = u >> 3;                          // candidate id
    const int q   = u & (SCH - 1);                   // s-chunk
    if (cc >= CAND) return;

    const float p0x = as_[2 * b], p0y = as_[2 * b + 1];
    const float p1x = ae_[2 * b], p1y = ae_[2 * b + 1];
    const float dx = p1x - p0x, dy = p1y - p0y;
    if (dx == 0.f && dy == 0.f) return;              // degenerate: window stays zero
    const float L  = sqrtf(dx * dx + dy * dy + 1e-12f);
    const float u0 = dx / L, u1 = dy / L;
    const float au0 = fabsf(u0), au1 = fabsf(u1);
    const int wx0 = (int)floorf(p1x - 32.f * au1);
    const int wy0 = (int)floorf(p1y - 32.f * au0);

    // ---- candidate cell on/near the landing line ----
    int m  = cc / 6;
    int e0 = cc - m * 6;
    int cx, cy;
    if (au1 >= au0) {                                // line moves fastest along x
        cx = wx0 + m;
        float tm  = (p1x - (float)cx) / u1;          // x(t) = p1x - t*u1
        float cyc = p1y + tm * u0;
        cy = min(max((int)floorf(cyc) - 2 + e0, wy0), wy0 + WM - 1);
    } else {
        cy = wy0 + m;
        float tm  = ((float)cy - p1y) / u0;          // y(t) = p1y + t*u0
        float cxc = p1x - tm * u1;
        cx = min(max((int)floorf(cxc) - 2 + e0, wx0), wx0 + WM - 1);
    }
    const float fcx = (float)cx, fcy = (float)cy;
    const float t_c = -(fcx - p1x) * u1 + (fcy - p1y) * u0;

    // ---- strip bounds over band-major lines ----
    const bool mj = (au0 >= au1);                    // band major axis = i
    float aA, aB, mb, ms;
    if (mj) {   // a(s) = p0x + s*u0 - t_c*u1 ; m_c(a) = p0y + (t_c + (a-p0x)*u1)/u0
        aA = p0x - 33.f * u0 - t_c * u1;
        aB = p0x + (L + 3.f) * u0 - t_c * u1;
        ms = u1 / u0;
        mb = p0y + (t_c - p0x * u1) / u0;
    } else {    // a(s) = p0y + s*u1 + t_c*u0 ; m_c(a) = p0x + ((a-p0y)*u0 - t_c)/u1
        aA = p0y - 33.f * u1 + t_c * u0;
        aB = p0y + (L + 3.f) * u1 + t_c * u0;
        ms = u0 / u1;
        mb = p0x + (-t_c - p0y * u0) / u1;
    }
    int alo = max((int)floorf(fminf(aA, aB)) - 2, 0);
    int ahi = min((int)ceilf (fmaxf(aA, aB)) + 2, NN - 1);
    int len = max(ahi - alo + 1, 0);
    int a0 = alo + (len * q) / SCH;
    int a1 = alo + (len * (q + 1)) / SCH;

    const float* ob = occ + ((size_t)b << 18);
    float acc = 0.f;
    for (int a = a0; a < a1; ++a) {
        int m0 = (int)floorf(mb + (float)a * ms) - 2;
        #pragma unroll
        for (int e = 0; e < 6; ++e) {
            int mm = m0 + e;
            if ((unsigned)mm > (unsigned)(NN - 1)) continue;
            int i = mj ? a  : mm;
            int j = mj ? mm : a;
            float rx = (float)i - p0x, ry = (float)j - p0y;
            float s = rx * u0 + ry * u1;
            float t = -rx * u1 + ry * u0;
            float xf = p1x - t * u1;                 // landing depends only on t
            float yf = p1y + t * u0;
            float wx = 1.f - fabsf(xf - fcx);
            float wy = 1.f - fabsf(yf - fcy);
            if (wx <= 0.f || wy <= 0.f) continue;    // hat self-gates
            if (fabsf(t) > 30.f || s < -30.f || s >= L) continue;
            float rho  = ob[i * NN + j];
            float mask = sigf(3.f - fabsf(t)) * sigf(s) * sigf(L - s);
            float moved = rho * mask;
            if (moved <= 1e-10f) continue;
            acc += wx * wy * moved;
        }
    }
    // combine the 8 s-chunks (consecutive lanes of one wave)
    acc += __shfl_xor(acc, 1);
    acc += __shfl_xor(acc, 2);
    acc += __shfl_xor(acc, 4);
    if (q == 0)
        ws[(size_t)b * WWIN + (cx - wx0) * WM + (cy - wy0)] = acc;
}

// ---------------- Pass 2: pure streaming base write (whole grid) ----------------
__global__ void __launch_bounds__(256) stream_kernel(
        const float* __restrict__ occ,
        const float* __restrict__ as_,
        const float* __restrict__ ae_,
        float* __restrict__ out) {
    int gid = blockIdx.x * 256 + threadIdx.x;   // float4-group id
    int b   = gid >> 16;
    int rem = gid & 65535;
    int i   = rem >> 7;
    int j0  = (rem & 127) << 2;

    const float p0x = as_[2 * b], p0y = as_[2 * b + 1];
    const float p1x = ae_[2 * b], p1y = ae_[2 * b + 1];
    const float dx = p1x - p0x, dy = p1y - p0y;
    const float L  = sqrtf(dx * dx + dy * dy + 1e-12f);
    const float u0 = dx / L, u1 = dy / L;
    const bool degen = (dx == 0.f && dy == 0.f);

    const float* ob   = occ + ((size_t)b << 18);
    float*       outb = out + ((size_t)b << 18);
    float4 o4 = *reinterpret_cast<const float4*>(ob + i * NN + j0);
    float4 v;
    v.x = base_elem(o4.x, i, j0 + 0, p0x, p0y, u0, u1, L, degen);
    v.y = base_elem(o4.y, i, j0 + 1, p0x, p0y, u0, u1, L, degen);
    v.z = base_elem(o4.z, i, j0 + 2, p0x, p0y, u0, u1, L, degen);
    v.w = base_elem(o4.w, i, j0 + 3, p0x, p0y, u0, u1, L, degen);
    *reinterpret_cast<float4*>(outb + i * NN + j0) = v;
}

// ---------------- Pass 3: per-batch region redistribution ----------------
#define RUNIT_INIT(K, UEXPR)                                                         \
    const int u##K  = (UEXPR);                                                       \
    const int li##K = u##K / RDU;                                                    \
    const int lj##K = (u##K - li##K * RDU) * 4;                                      \
    float4 r##K, vm##K;                                                              \
    {                                                                                \
        int gi = rx0 + li##K;                                                        \
        int gj = ry0 + lj##K;                                                        \
        bool rok = (gi >= 0) && (gi < NN);                                           \
        vm##K.x = (rok && (unsigned)(gj + 0) < NN) ? 1.f : 0.f;                      \
        vm##K.y = (rok && (unsigned)(gj + 1) < NN) ? 1.f : 0.f;                      \
        vm##K.z = (rok && (unsigned)(gj + 2) < NN) ? 1.f : 0.f;                      \
        vm##K.w = (rok && (unsigned)(gj + 3) < NN) ? 1.f : 0.f;                      \
        float4 v = make_float4(0.f, 0.f, 0.f, 0.f);                                  \
        if (rok) {                                                                   \
            const float* orow = outb + gi * NN;                                      \
            int cx = li##K - 12;                                                     \
            bool cxok = (unsigned)cx < (unsigned)WM;                                 \
            float* vp = (float*)&v;                                                  \
            const float* vmp = (const float*)&vm##K;                                 \
            _Pragma("unroll")                                                        \
            for (int e = 0; e < 4; ++e) {                                            \
                if (vmp[e] > 0.f) {                                                  \
                    float t = orow[gj + e];                                          \
                    int cy = lj##K + e - 12;                                         \
                    if (cxok && (unsigned)cy < (unsigned)WM) t += wsb[cx * WM + cy]; \
                    vp[e] = t;                                                       \
                }                                                                    \
            }                                                                        \
        }                                                                            \
        r##K = v;                                                                    \
    }                                                                                \
    const int rA##K = min(max(li##K + oi, 0), RD - 1);                               \
    const int dB##K = (min(max(li##K + oi - 1, 0), RD - 1) - rA##K) * RST;           \
    const int wa##K = li##K * RST + lj##K;                                           \
    const int aA0##K = rA##K * RST + max(lj##K + oj - 1, 0);                         \
    const int aA1##K = rA##K * RST + (lj##K + oj + 0);                               \
    const int aA2##K = rA##K * RST + (lj##K + oj + 1);                               \
    const int aA3##K = rA##K * RST + (lj##K + oj + 2);                               \
    const int aA4##K = rA##K * RST + min(lj##K + oj + 3, RD - 1);

#define RUNIT_STORE(K)                                                               \
    smem[wa##K + 0] = fmaxf(r##K.x - 1.f, 0.f);                                      \
    smem[wa##K + 1] = fmaxf(r##K.y - 1.f, 0.f);                                      \
    smem[wa##K + 2] = fmaxf(r##K.z - 1.f, 0.f);                                      \
    smem[wa##K + 3] = fmaxf(r##K.w - 1.f, 0.f);

#define RUNIT_GATHER(K) {                                                            \
    float eA0 = smem[aA0##K], eA1 = smem[aA1##K], eA2 = smem[aA2##K];                \
    float eA3 = smem[aA3##K], eA4 = smem[aA4##K];                                    \
    float eB0 = smem[aA0##K + dB##K], eB1 = smem[aA1##K + dB##K];                    \
    float eB2 = smem[aA2##K + dB##K], eB3 = smem[aA3##K + dB##K];                    \
    float eB4 = smem[aA4##K + dB##K];                                                \
    float g;                                                                         \
    g = wA0 * (wA1 * eA1 + wB1 * eA0) + wB0 * (wA1 * eB1 + wB1 * eB0);               \
    r##K.x = (fminf(r##K.x, 1.f) + g) * vm##K.x;                                     \
    g = wA0 * (wA1 * eA2 + wB1 * eA1) + wB0 * (wA1 * eB2 + wB1 * eB1);               \
    r##K.y = (fminf(r##K.y, 1.f) + g) * vm##K.y;                                     \
    g = wA0 * (wA1 * eA3 + wB1 * eA2) + wB0 * (wA1 * eB3 + wB1 * eB2);               \
    r##K.z = (fminf(r##K.z, 1.f) + g) * vm##K.z;                                     \
    g = wA0 * (wA1 * eA4 + wB1 * eA3) + wB0 * (wA1 * eB4 + wB1 * eB3);               \
    r##K.w = (fminf(r##K.w, 1.f) + g) * vm##K.w; }

#define RUNIT_WRITE(K) {                                                             \
    int gi = rx0 + li##K;                                                            \
    if (gi >= 0 && gi < NN) {                                                        \
        float* orow = outb + gi * NN;                                                \
        int gj = ry0 + lj##K;                                                        \
        if (vm##K.x > 0.f) orow[gj + 0] = r##K.x;                                    \
        if (vm##K.y > 0.f) orow[gj + 1] = r##K.y;                                    \
        if (vm##K.z > 0.f) orow[gj + 2] = r##K.z;                                    \
        if (vm##K.w > 0.f) orow[gj + 3] = r##K.w;                                    \
    } }

__global__ void __launch_bounds__(RTPB) redist_kernel(
        const float* __restrict__ ws,
        const float* __restrict__ as_,
        const float* __restrict__ ae_,
        float* __restrict__ out) {
    __shared__ float smem[RD * RST];
    const int b   = blockIdx.x;
    const int tid = threadIdx.x;

    const float p0x = as_[2 * b], p0y = as_[2 * b + 1];
    const float p1x = ae_[2 * b], p1y = ae_[2 * b + 1];
    const float dx = p1x - p0x, dy = p1y - p0y;
    const float L  = sqrtf(dx * dx + dy * dy + 1e-12f);
    const float pu0 = dx / L, pu1 = dy / L;
    const int wx0 = (int)floorf(p1x - 32.f * fabsf(pu1));  // identical expr to splat
    const int wy0 = (int)floorf(p1y - 32.f * fabsf(pu0));
    const int rx0 = wx0 - 12;
    const int ry0 = wy0 - 12;
    const float dn  = sqrtf(dx * dx + dy * dy);
    const bool active = dn > 1e-6f;
    const float rdn = fmaxf(dn, 1e-6f);
    const float ru0 = dx / rdn, ru1 = dy / rdn;
    const float s0f = floorf(ru0), s1f = floorf(ru1);
    const float f0 = ru0 - s0f, f1 = ru1 - s1f;
    const int oi = -(int)s0f;
    const int oj = -(int)s1f;
    const float wA0 = 1.f - f0, wB0 = f0;
    const float wA1 = 1.f - f1, wB1 = f1;

    const float* wsb  = ws  + (size_t)b * WWIN;
    float*       outb = out + ((size_t)b << 18);

    RUNIT_INIT(0, tid)
    RUNIT_INIT(1, tid + RTPB)
    RUNIT_INIT(2, min(tid + 2 * RTPB, RUNITS - 1))

    if (active) {
        for (int it = 0; it < ITERS; ++it) {
            RUNIT_STORE(0) RUNIT_STORE(1) RUNIT_STORE(2)
            __syncthreads();
            RUNIT_GATHER(0) RUNIT_GATHER(1) RUNIT_GATHER(2)
            __syncthreads();
        }
    }

    RUNIT_WRITE(0)
    RUNIT_WRITE(1)
    RUNIT_WRITE(2)
}

extern "C" void kernel_launch(void* const* d_in, const int* in_sizes, int n_in,
                              void* d_out, int out_size, void* d_ws, size_t ws_size,
                              hipStream_t stream) {
    const float* occ = (const float*)d_in[0];
    const float* as_ = (const float*)d_in[1];
    const float* ae_ = (const float*)d_in[2];
    float* out = (float*)d_out;
    float* ws  = (float*)d_ws;

    hipMemsetAsync(ws, 0, (size_t)BB * WWIN * sizeof(float), stream);

    splat_kernel<<<BB * CBLK, 256, 0, stream>>>(occ, as_, ae_, ws);

    const int stream_blocks = (BB * NN2 / 4) / 256;   // 16384
    stream_kernel<<<stream_blocks, 256, 0, stream>>>(occ, as_, ae_, out);

    redist_kernel<<<BB, RTPB, 0, stream>>>(ws, as_, ae_, out);
}

// Round 10
// 105.379 us; speedup vs baseline: 1.6356x; 1.6356x over previous
//
#include <hip/hip_runtime.h>

#define NN   512
#define NN2  (NN * NN)
#define BB   64
#define ITERS 10
#define WM   68                    // landing-window dim & stride
#define WWIN (WM * WM)             // 4624 floats
#define SBLK 4                     // splat blocks per batch (1 per CU)
#define STPB 1024                  // splat threads per block
#define CPL 128                    // cells enumerated per line (width<=89 guaranteed)

// redistribution region: window (68) + 12 halo each side
#define RD   92
#define RDU  23                    // RD/4 float4-units per row
#define RUNITS (RD * RDU)          // 2116
#define RST  97                    // LDS row stride (odd -> bank spread)
#define RTPB 1024

__device__ __forceinline__ float sigf(float x) { return 1.0f / (1.0f + __expf(-x)); }

__device__ __forceinline__ float maskf(float s, float t, float L) {
    if (fabsf(t) > 30.f || s < -30.f || s > L + 30.f) return 0.f;
    return sigf(3.f - fabsf(t)) * sigf(s) * sigf(L - s);
}

// base (pushed density without landing mass). s>=L or degenerate => self-splat => rho.
__device__ __forceinline__ float base_elem(float o, int gi, int gj,
        float p0x, float p0y, float pu0, float pu1, float L, bool degen) {
    float rx = (float)gi - p0x, ry = (float)gj - p0y;
    float s = rx * pu0 + ry * pu1;
    float t = -rx * pu1 + ry * pu0;
    float m = maskf(s, t, L);
    return (degen || s >= L) ? o : o * (1.f - m);
}

// ---------------- Pass 1: scatter splat, 4 blocks/batch, private windows --------
// Band |t|<=30 has minor-width <= 60/|u_major|+slack <= 89 cells; a 128-cell
// window around the affine per-line center (slope/width hoisted, no divides in
// the loop) is a provable superset. Exact per-cell tests gate all work.
// Each block accumulates into its own LDS window and writes it PRIVATELY to
// ws[blockIdx] (plain stores, no global atomics, no memset); redist sums the
// SBLK windows on load.
__global__ void __launch_bounds__(STPB) splat_kernel(
        const float* __restrict__ occ,
        const float* __restrict__ as_,
        const float* __restrict__ ae_,
        float* __restrict__ ws) {
    __shared__ float win[WWIN];
    const int b   = blockIdx.x >> 2;
    const int qb  = blockIdx.x & (SBLK - 1);
    const int tid = threadIdx.x;

    const float p0x = as_[2 * b], p0y = as_[2 * b + 1];
    const float p1x = ae_[2 * b], p1y = ae_[2 * b + 1];
    const float dx = p1x - p0x, dy = p1y - p0y;
    const float L  = sqrtf(dx * dx + dy * dy + 1e-12f);
    const float u0 = dx / L, u1 = dy / L;
    const float au0 = fabsf(u0), au1 = fabsf(u1);
    const int wx0 = (int)floorf(p1x - 32.f * au1);
    const int wy0 = (int)floorf(p1y - 32.f * au0);
    const bool degen = (dx == 0.f && dy == 0.f);

    for (int k = tid; k < WWIN; k += STPB) win[k] = 0.f;
    __syncthreads();

    if (!degen) {
        const float* ob = occ + ((size_t)b << 18);
        const bool mj = (au0 >= au1);           // major axis = i when au0>=au1
        const float umaj = mj ? u0 : u1;
        const float rr   = (mj ? u1 : u0) / umaj;   // minor/major slope
        const float ww   = 30.f / fabsf(umaj) + 2.f;
        const float pmaj = mj ? p0x : p0y;
        const float pmin = mj ? p0y : p0x;

        // 16384 cells per block = 128 lines x 128 offs; wave layout = 16-cell
        // minor runs x 4 lines (coalesced loads, t-spread >= 11 per run).
        #pragma unroll 4
        for (int k = 0; k < 16; ++k) {
            int c     = k * STPB + tid;          // 0..16383
            int lane16 = c & 15;
            int grp   = c >> 4;                  // 0..1023
            int line  = grp & 127;
            int chunk = grp >> 7;                // 0..7
            int off   = (chunk << 4) | lane16;   // 0..127
            int a     = qb * 128 + line;         // major coord 0..511
            float fa  = (float)a;
            float cen = pmin + (fa - pmaj) * rr;
            int cm = (int)floorf(cen - ww) + off;
            if ((unsigned)cm > (unsigned)(NN - 1)) continue;
            int i = mj ? a  : cm;
            int j = mj ? cm : a;
            float rx = (float)i - p0x, ry = (float)j - p0y;
            float s = rx * u0 + ry * u1;
            float t = -rx * u1 + ry * u0;
            if (fabsf(t) > 30.f || s < -30.f || s >= L) continue;  // s>=L: self-splat
            float rho = ob[i * NN + j];
            float mask  = sigf(3.f - fabsf(t)) * sigf(s) * sigf(L - s);
            float moved = rho * mask;
            if (moved <= 1e-10f) continue;
            float xf = p1x - t * u1;    // landing depends only on t
            float yf = p1y + t * u0;
            float x0 = floorf(xf), y0 = floorf(yf);
            float fx = xf - x0, fy = yf - y0;
            int base = ((int)x0 - wx0) * WM + ((int)y0 - wy0);
            atomicAdd(&win[base],          (1.f - fx) * (1.f - fy) * moved);
            atomicAdd(&win[base + 1],      (1.f - fx) * fy * moved);
            atomicAdd(&win[base + WM],     fx * (1.f - fy) * moved);
            atomicAdd(&win[base + WM + 1], fx * fy * moved);
        }
    }
    __syncthreads();
    float* wsb = ws + (size_t)blockIdx.x * WWIN;   // private window, plain stores
    for (int k = tid; k < WWIN; k += STPB) wsb[k] = win[k];
}

// ---------------- Pass 2: pure streaming base write (whole grid) ----------------
__global__ void __launch_bounds__(256) stream_kernel(
        const float* __restrict__ occ,
        const float* __restrict__ as_,
        const float* __restrict__ ae_,
        float* __restrict__ out) {
    int gid = blockIdx.x * 256 + threadIdx.x;   // float4-group id
    int b   = gid >> 16;
    int rem = gid & 65535;
    int i   = rem >> 7;
    int j0  = (rem & 127) << 2;

    const float p0x = as_[2 * b], p0y = as_[2 * b + 1];
    const float p1x = ae_[2 * b], p1y = ae_[2 * b + 1];
    const float dx = p1x - p0x, dy = p1y - p0y;
    const float L  = sqrtf(dx * dx + dy * dy + 1e-12f);
    const float u0 = dx / L, u1 = dy / L;
    const bool degen = (dx == 0.f && dy == 0.f);

    const float* ob   = occ + ((size_t)b << 18);
    float*       outb = out + ((size_t)b << 18);
    float4 o4 = *reinterpret_cast<const float4*>(ob + i * NN + j0);
    float4 v;
    v.x = base_elem(o4.x, i, j0 + 0, p0x, p0y, u0, u1, L, degen);
    v.y = base_elem(o4.y, i, j0 + 1, p0x, p0y, u0, u1, L, degen);
    v.z = base_elem(o4.z, i, j0 + 2, p0x, p0y, u0, u1, L, degen);
    v.w = base_elem(o4.w, i, j0 + 3, p0x, p0y, u0, u1, L, degen);
    *reinterpret_cast<float4*>(outb + i * NN + j0) = v;
}

// ---------------- Pass 3: per-batch region redistribution ----------------
#define RUNIT_INIT(K, UEXPR)                                                         \
    const int u##K  = (UEXPR);                                                       \
    const int li##K = u##K / RDU;                                                    \
    const int lj##K = (u##K - li##K * RDU) * 4;                                      \
    float4 r##K, vm##K;                                                              \
    {                                                                                \
        int gi = rx0 + li##K;                                                        \
        int gj = ry0 + lj##K;                                                        \
        bool rok = (gi >= 0) && (gi < NN);                                           \
        vm##K.x = (rok && (unsigned)(gj + 0) < NN) ? 1.f : 0.f;                      \
        vm##K.y = (rok && (unsigned)(gj + 1) < NN) ? 1.f : 0.f;                      \
        vm##K.z = (rok && (unsigned)(gj + 2) < NN) ? 1.f : 0.f;                      \
        vm##K.w = (rok && (unsigned)(gj + 3) < NN) ? 1.f : 0.f;                      \
        float4 v = make_float4(0.f, 0.f, 0.f, 0.f);                                  \
        if (rok) {                                                                   \
            const float* orow = outb + gi * NN;                                      \
            int cx = li##K - 12;                                                     \
            bool cxok = (unsigned)cx < (unsigned)WM;                                 \
            float* vp = (float*)&v;                                                  \
            const float* vmp = (const float*)&vm##K;                                 \
            _Pragma("unroll")                                                        \
            for (int e = 0; e < 4; ++e) {                                            \
                if (vmp[e] > 0.f) {                                                  \
                    float t = orow[gj + e];                                          \
                    int cy = lj##K + e - 12;                                         \
                    if (cxok && (unsigned)cy < (unsigned)WM) {                       \
                        int widx = cx * WM + cy;                                     \
                        t += wsb[widx] + wsb[WWIN + widx]                            \
                           + wsb[2 * WWIN + widx] + wsb[3 * WWIN + widx];            \
                    }                                                                \
                    vp[e] = t;                                                       \
                }                                                                    \
            }                                                                        \
        }                                                                            \
        r##K = v;                                                                    \
    }                                                                                \
    const int rA##K = min(max(li##K + oi, 0), RD - 1);                               \
    const int dB##K = (min(max(li##K + oi - 1, 0), RD - 1) - rA##K) * RST;           \
    const int wa##K = li##K * RST + lj##K;                                           \
    const int aA0##K = rA##K * RST + max(lj##K + oj - 1, 0);                         \
    const int aA1##K = rA##K * RST + (lj##K + oj + 0);                               \
    const int aA2##K = rA##K * RST + (lj##K + oj + 1);                               \
    const int aA3##K = rA##K * RST + (lj##K + oj + 2);                               \
    const int aA4##K = rA##K * RST + min(lj##K + oj + 3, RD - 1);

#define RUNIT_STORE(K)                                                               \
    smem[wa##K + 0] = fmaxf(r##K.x - 1.f, 0.f);                                      \
    smem[wa##K + 1] = fmaxf(r##K.y - 1.f, 0.f);                                      \
    smem[wa##K + 2] = fmaxf(r##K.z - 1.f, 0.f);                                      \
    smem[wa##K + 3] = fmaxf(r##K.w - 1.f, 0.f);

#define RUNIT_GATHER(K) {                                                            \
    float eA0 = smem[aA0##K], eA1 = smem[aA1##K], eA2 = smem[aA2##K];                \
    float eA3 = smem[aA3##K], eA4 = smem[aA4##K];                                    \
    float eB0 = smem[aA0##K + dB##K], eB1 = smem[aA1##K + dB##K];                    \
    float eB2 = smem[aA2##K + dB##K], eB3 = smem[aA3##K + dB##K];                    \
    float eB4 = smem[aA4##K + dB##K];                                                \
    float g;                                                                         \
    g = wA0 * (wA1 * eA1 + wB1 * eA0) + wB0 * (wA1 * eB1 + wB1 * eB0);               \
    r##K.x = (fminf(r##K.x, 1.f) + g) * vm##K.x;                                     \
    g = wA0 * (wA1 * eA2 + wB1 * eA1) + wB0 * (wA1 * eB2 + wB1 * eB1);               \
    r##K.y = (fminf(r##K.y, 1.f) + g) * vm##K.y;                                     \
    g = wA0 * (wA1 * eA3 + wB1 * eA2) + wB0 * (wA1 * eB3 + wB1 * eB2);               \
    r##K.z = (fminf(r##K.z, 1.f) + g) * vm##K.z;                                     \
    g = wA0 * (wA1 * eA4 + wB1 * eA3) + wB0 * (wA1 * eB4 + wB1 * eB3);               \
    r##K.w = (fminf(r##K.w, 1.f) + g) * vm##K.w; }

#define RUNIT_WRITE(K) {                                                             \
    int gi = rx0 + li##K;                                                            \
    if (gi >= 0 && gi < NN) {                                                        \
        float* orow = outb + gi * NN;                                                \
        int gj = ry0 + lj##K;                                                        \
        if (vm##K.x > 0.f) orow[gj + 0] = r##K.x;                                    \
        if (vm##K.y > 0.f) orow[gj + 1] = r##K.y;                                    \
        if (vm##K.z > 0.f) orow[gj + 2] = r##K.z;                                    \
        if (vm##K.w > 0.f) orow[gj + 3] = r##K.w;                                    \
    } }

__global__ void __launch_bounds__(RTPB) redist_kernel(
        const float* __restrict__ ws,
        const float* __restrict__ as_,
        const float* __restrict__ ae_,
        float* __restrict__ out) {
    __shared__ float smem[RD * RST];
    const int b   = blockIdx.x;
    const int tid = threadIdx.x;

    const float p0x = as_[2 * b], p0y = as_[2 * b + 1];
    const float p1x = ae_[2 * b], p1y = ae_[2 * b + 1];
    const float dx = p1x - p0x, dy = p1y - p0y;
    const float L  = sqrtf(dx * dx + dy * dy + 1e-12f);
    const float pu0 = dx / L, pu1 = dy / L;
    const int wx0 = (int)floorf(p1x - 32.f * fabsf(pu1));  // identical expr to splat
    const int wy0 = (int)floorf(p1y - 32.f * fabsf(pu0));
    const int rx0 = wx0 - 12;
    const int ry0 = wy0 - 12;
    const float dn  = sqrtf(dx * dx + dy * dy);
    const bool active = dn > 1e-6f;
    const float rdn = fmaxf(dn, 1e-6f);
    const float ru0 = dx / rdn, ru1 = dy / rdn;
    const float s0f = floorf(ru0), s1f = floorf(ru1);
    const float f0 = ru0 - s0f, f1 = ru1 - s1f;
    const int oi = -(int)s0f;
    const int oj = -(int)s1f;
    const float wA0 = 1.f - f0, wB0 = f0;
    const float wA1 = 1.f - f1, wB1 = f1;

    const float* wsb  = ws  + (size_t)b * (SBLK * WWIN);
    float*       outb = out + ((size_t)b << 18);

    RUNIT_INIT(0, tid)
    RUNIT_INIT(1, tid + RTPB)
    RUNIT_INIT(2, min(tid + 2 * RTPB, RUNITS - 1))

    if (active) {
        for (int it = 0; it < ITERS; ++it) {
            RUNIT_STORE(0) RUNIT_STORE(1) RUNIT_STORE(2)
            __syncthreads();
            RUNIT_GATHER(0) RUNIT_GATHER(1) RUNIT_GATHER(2)
            __syncthreads();
        }
    }

    RUNIT_WRITE(0)
    RUNIT_WRITE(1)
    RUNIT_WRITE(2)
}

extern "C" void kernel_launch(void* const* d_in, const int* in_sizes, int n_in,
                              void* d_out, int out_size, void* d_ws, size_t ws_size,
                              hipStream_t stream) {
    const float* occ = (const float*)d_in[0];
    const float* as_ = (const float*)d_in[1];
    const float* ae_ = (const float*)d_in[2];
    float* out = (float*)d_out;
    float* ws  = (float*)d_ws;

    splat_kernel<<<BB * SBLK, STPB, 0, stream>>>(occ, as_, ae_, ws);

    const int stream_blocks = (BB * NN2 / 4) / 256;   // 16384
    stream_kernel<<<stream_blocks, 256, 0, stream>>>(occ, as_, ae_, out);

    redist_kernel<<<BB, RTPB, 0, stream>>>(ws, as_, ae_, out);
}

// Round 11
// 80.049 us; speedup vs baseline: 2.1531x; 1.3164x over previous
//
#include <hip/hip_runtime.h>

#define NN   512
#define NN2  (NN * NN)
#define BB   64
#define ITERS 10
#define WM   68                    // landing-window dim & stride
#define WWIN (WM * WM)             // 4624 floats
#define SBLK 16                    // splat blocks per batch (private windows)
#define LPB  32                    // major lines per splat block (512/SBLK)
#define NSPLAT (BB * SBLK)         // 1024 splat blocks
#define NSTREAM 8192               // stream blocks (4.19M float4-groups / 512)
#define FTPB 512                   // fused kernel threads per block

// redistribution region: window (68) + 12 halo each side
#define RD   92
#define RDU  23                    // RD/4 float4-units per row
#define RUNITS (RD * RDU)          // 2116
#define RST  97                    // LDS row stride (odd -> bank spread)
#define RTPB 1024

__device__ __forceinline__ float sigf(float x) { return 1.0f / (1.0f + __expf(-x)); }

__device__ __forceinline__ float maskf(float s, float t, float L) {
    if (fabsf(t) > 30.f || s < -30.f || s > L + 30.f) return 0.f;
    return sigf(3.f - fabsf(t)) * sigf(s) * sigf(L - s);
}

// base (pushed density without landing mass). s>=L or degenerate => self-splat => rho.
__device__ __forceinline__ float base_elem(float o, int gi, int gj,
        float p0x, float p0y, float pu0, float pu1, float L, bool degen) {
    float rx = (float)gi - p0x, ry = (float)gj - p0y;
    float s = rx * pu0 + ry * pu1;
    float t = -rx * pu1 + ry * pu0;
    float m = maskf(s, t, L);
    return (degen || s >= L) ? o : o * (1.f - m);
}

// ---------------- Pass 1 (fused): splat blocks + stream blocks in ONE dispatch ----
// Splat (latency-bound, few blocks) co-resides with stream (BW-bound, many
// blocks): splat's dependency-chain stalls are filled by stream waves, and its
// runtime hides under the stream's HBM floor instead of serializing.
__global__ void __launch_bounds__(FTPB) fused_kernel(
        const float* __restrict__ occ,
        const float* __restrict__ as_,
        const float* __restrict__ ae_,
        float* __restrict__ ws,
        float* __restrict__ out) {
    __shared__ float win[WWIN];
    const int bid = blockIdx.x;
    const int tid = threadIdx.x;

    if (bid < NSPLAT) {
        // ---------------- splat block ----------------
        const int b  = bid >> 4;
        const int qb = bid & (SBLK - 1);

        const float p0x = as_[2 * b], p0y = as_[2 * b + 1];
        const float p1x = ae_[2 * b], p1y = ae_[2 * b + 1];
        const float dx = p1x - p0x, dy = p1y - p0y;
        const float L  = sqrtf(dx * dx + dy * dy + 1e-12f);
        const float u0 = dx / L, u1 = dy / L;
        const float au0 = fabsf(u0), au1 = fabsf(u1);
        const int wx0 = (int)floorf(p1x - 32.f * au1);
        const int wy0 = (int)floorf(p1y - 32.f * au0);
        const bool degen = (dx == 0.f && dy == 0.f);

        for (int k = tid; k < WWIN; k += FTPB) win[k] = 0.f;
        __syncthreads();

        if (!degen) {
            const float* ob = occ + ((size_t)b << 18);
            const bool mj = (au0 >= au1);           // major axis = i when au0>=au1
            const float umaj = mj ? u0 : u1;
            const float rr   = (mj ? u1 : u0) / umaj;   // minor/major slope
            const float ww   = 30.f / fabsf(umaj) + 2.f;
            const float pmaj = mj ? p0x : p0y;
            const float pmin = mj ? p0y : p0x;

            // 4096 cells = 32 lines x 128 offs, 8 per thread.
            // mj=true: 64-lane contiguous minor runs (coalesced; t-spread>=45).
            // mj=false: 16-off x 4-line groups (partial coalesce; t-spread>=11).
            #pragma unroll
            for (int k = 0; k < 8; ++k) {
                int line, off;
                if (mj) {
                    off  = tid & 127;
                    line = 4 * k + (tid >> 7);
                } else {
                    off  = k * 16 + (tid & 15);
                    line = tid >> 4;
                }
                int a    = qb * LPB + line;          // major coord 0..511
                float fa = (float)a;
                float cen = pmin + (fa - pmaj) * rr;
                int cm = (int)floorf(cen - ww) + off;
                if ((unsigned)cm > (unsigned)(NN - 1)) continue;
                int i = mj ? a  : cm;
                int j = mj ? cm : a;
                float rx = (float)i - p0x, ry = (float)j - p0y;
                float s = rx * u0 + ry * u1;
                float t = -rx * u1 + ry * u0;
                if (fabsf(t) > 30.f || s < -30.f || s >= L) continue;  // s>=L: self
                float rho = ob[i * NN + j];
                float mask  = sigf(3.f - fabsf(t)) * sigf(s) * sigf(L - s);
                float moved = rho * mask;
                if (moved <= 1e-10f) continue;
                float xf = p1x - t * u1;    // landing depends only on t
                float yf = p1y + t * u0;
                float x0 = floorf(xf), y0 = floorf(yf);
                float fx = xf - x0, fy = yf - y0;
                int base = ((int)x0 - wx0) * WM + ((int)y0 - wy0);
                atomicAdd(&win[base],          (1.f - fx) * (1.f - fy) * moved);
                atomicAdd(&win[base + 1],      (1.f - fx) * fy * moved);
                atomicAdd(&win[base + WM],     fx * (1.f - fy) * moved);
                atomicAdd(&win[base + WM + 1], fx * fy * moved);
            }
        }
        __syncthreads();
        float* wsb = ws + (size_t)bid * WWIN;   // private window, plain stores
        for (int k = tid; k < WWIN; k += FTPB) wsb[k] = win[k];
    } else {
        // ---------------- stream block: base write, 1 float4/thread ----------------
        int gid = (bid - NSPLAT) * FTPB + tid;   // 0..4194303
        int b   = gid >> 16;
        int rem = gid & 65535;
        int i   = rem >> 7;
        int j0  = (rem & 127) << 2;

        const float p0x = as_[2 * b], p0y = as_[2 * b + 1];
        const float p1x = ae_[2 * b], p1y = ae_[2 * b + 1];
        const float dx = p1x - p0x, dy = p1y - p0y;
        const float L  = sqrtf(dx * dx + dy * dy + 1e-12f);
        const float u0 = dx / L, u1 = dy / L;
        const bool degen = (dx == 0.f && dy == 0.f);

        const float* ob   = occ + ((size_t)b << 18);
        float*       outb = out + ((size_t)b << 18);
        float4 o4 = *reinterpret_cast<const float4*>(ob + i * NN + j0);
        float4 v;
        v.x = base_elem(o4.x, i, j0 + 0, p0x, p0y, u0, u1, L, degen);
        v.y = base_elem(o4.y, i, j0 + 1, p0x, p0y, u0, u1, L, degen);
        v.z = base_elem(o4.z, i, j0 + 2, p0x, p0y, u0, u1, L, degen);
        v.w = base_elem(o4.w, i, j0 + 3, p0x, p0y, u0, u1, L, degen);
        *reinterpret_cast<float4*>(outb + i * NN + j0) = v;
    }
}

// ---------------- Pass 2: per-batch region redistribution ----------------
#define RUNIT_INIT(K, UEXPR)                                                         \
    const int u##K  = (UEXPR);                                                       \
    const int li##K = u##K / RDU;                                                    \
    const int lj##K = (u##K - li##K * RDU) * 4;                                      \
    float4 r##K, vm##K;                                                              \
    {                                                                                \
        int gi = rx0 + li##K;                                                        \
        int gj = ry0 + lj##K;                                                        \
        bool rok = (gi >= 0) && (gi < NN);                                           \
        vm##K.x = (rok && (unsigned)(gj + 0) < NN) ? 1.f : 0.f;                      \
        vm##K.y = (rok && (unsigned)(gj + 1) < NN) ? 1.f : 0.f;                      \
        vm##K.z = (rok && (unsigned)(gj + 2) < NN) ? 1.f : 0.f;                      \
        vm##K.w = (rok && (unsigned)(gj + 3) < NN) ? 1.f : 0.f;                      \
        float4 v = make_float4(0.f, 0.f, 0.f, 0.f);                                  \
        if (rok) {                                                                   \
            const float* orow = outb + gi * NN;                                      \
            int cx = li##K - 12;                                                     \
            bool cxok = (unsigned)cx < (unsigned)WM;                                 \
            float* vp = (float*)&v;                                                  \
            const float* vmp = (const float*)&vm##K;                                 \
            _Pragma("unroll")                                                        \
            for (int e = 0; e < 4; ++e) {                                            \
                if (vmp[e] > 0.f) {                                                  \
                    float t = orow[gj + e];                                          \
                    int cy = lj##K + e - 12;                                         \
                    if (cxok && (unsigned)cy < (unsigned)WM) t += winsum[cx * WM + cy]; \
                    vp[e] = t;                                                       \
                }                                                                    \
            }                                                                        \
        }                                                                            \
        r##K = v;                                                                    \
    }                                                                                \
    const int rA##K = min(max(li##K + oi, 0), RD - 1);                               \
    const int dB##K = (min(max(li##K + oi - 1, 0), RD - 1) - rA##K) * RST;           \
    const int wa##K = li##K * RST + lj##K;                                           \
    const int aA0##K = rA##K * RST + max(lj##K + oj - 1, 0);                         \
    const int aA1##K = rA##K * RST + (lj##K + oj + 0);                               \
    const int aA2##K = rA##K * RST + (lj##K + oj + 1);                               \
    const int aA3##K = rA##K * RST + (lj##K + oj + 2);                               \
    const int aA4##K = rA##K * RST + min(lj##K + oj + 3, RD - 1);

#define RUNIT_STORE(K)                                                               \
    smem[wa##K + 0] = fmaxf(r##K.x - 1.f, 0.f);                                      \
    smem[wa##K + 1] = fmaxf(r##K.y - 1.f, 0.f);                                      \
    smem[wa##K + 2] = fmaxf(r##K.z - 1.f, 0.f);                                      \
    smem[wa##K + 3] = fmaxf(r##K.w - 1.f, 0.f);

#define RUNIT_GATHER(K) {                                                            \
    float eA0 = smem[aA0##K], eA1 = smem[aA1##K], eA2 = smem[aA2##K];                \
    float eA3 = smem[aA3##K], eA4 = smem[aA4##K];                                    \
    float eB0 = smem[aA0##K + dB##K], eB1 = smem[aA1##K + dB##K];                    \
    float eB2 = smem[aA2##K + dB##K], eB3 = smem[aA3##K + dB##K];                    \
    float eB4 = smem[aA4##K + dB##K];                                                \
    float g;                                                                         \
    g = wA0 * (wA1 * eA1 + wB1 * eA0) + wB0 * (wA1 * eB1 + wB1 * eB0);               \
    r##K.x = (fminf(r##K.x, 1.f) + g) * vm##K.x;                                     \
    g = wA0 * (wA1 * eA2 + wB1 * eA1) + wB0 * (wA1 * eB2 + wB1 * eB1);               \
    r##K.y = (fminf(r##K.y, 1.f) + g) * vm##K.y;                                     \
    g = wA0 * (wA1 * eA3 + wB1 * eA2) + wB0 * (wA1 * eB3 + wB1 * eB2);               \
    r##K.z = (fminf(r##K.z, 1.f) + g) * vm##K.z;                                     \
    g = wA0 * (wA1 * eA4 + wB1 * eA3) + wB0 * (wA1 * eB4 + wB1 * eB3);               \
    r##K.w = (fminf(r##K.w, 1.f) + g) * vm##K.w; }

#define RUNIT_WRITE(K) {                                                             \
    int gi = rx0 + li##K;                                                            \
    if (gi >= 0 && gi < NN) {                                                        \
        float* orow = outb + gi * NN;                                                \
        int gj = ry0 + lj##K;                                                        \
        if (vm##K.x > 0.f) orow[gj + 0] = r##K.x;                                    \
        if (vm##K.y > 0.f) orow[gj + 1] = r##K.y;                                    \
        if (vm##K.z > 0.f) orow[gj + 2] = r##K.z;                                    \
        if (vm##K.w > 0.f) orow[gj + 3] = r##K.w;                                    \
    } }

__global__ void __launch_bounds__(RTPB) redist_kernel(
        const float* __restrict__ ws,
        const float* __restrict__ as_,
        const float* __restrict__ ae_,
        float* __restrict__ out) {
    __shared__ float smem[RD * RST];
    __shared__ float winsum[WWIN];
    const int b   = blockIdx.x;
    const int tid = threadIdx.x;

    const float p0x = as_[2 * b], p0y = as_[2 * b + 1];
    const float p1x = ae_[2 * b], p1y = ae_[2 * b + 1];
    const float dx = p1x - p0x, dy = p1y - p0y;
    const float L  = sqrtf(dx * dx + dy * dy + 1e-12f);
    const float pu0 = dx / L, pu1 = dy / L;
    const int wx0 = (int)floorf(p1x - 32.f * fabsf(pu1));  // identical expr to splat
    const int wy0 = (int)floorf(p1y - 32.f * fabsf(pu0));
    const int rx0 = wx0 - 12;
    const int ry0 = wy0 - 12;
    const float dn  = sqrtf(dx * dx + dy * dy);
    const bool active = dn > 1e-6f;
    const float rdn = fmaxf(dn, 1e-6f);
    const float ru0 = dx / rdn, ru1 = dy / rdn;
    const float s0f = floorf(ru0), s1f = floorf(ru1);
    const float f0 = ru0 - s0f, f1 = ru1 - s1f;
    const int oi = -(int)s0f;
    const int oj = -(int)s1f;
    const float wA0 = 1.f - f0, wB0 = f0;
    const float wA1 = 1.f - f1, wB1 = f1;

    const float* wsb  = ws  + (size_t)b * (SBLK * WWIN);
    float*       outb = out + ((size_t)b << 18);

    // pre-sum the SBLK private windows (coalesced) into LDS
    for (int k = tid; k < WWIN; k += RTPB) {
        float s = 0.f;
        #pragma unroll
        for (int w = 0; w < SBLK; ++w) s += wsb[w * WWIN + k];
        winsum[k] = s;
    }
    __syncthreads();

    RUNIT_INIT(0, tid)
    RUNIT_INIT(1, tid + RTPB)
    RUNIT_INIT(2, min(tid + 2 * RTPB, RUNITS - 1))

    if (active) {
        for (int it = 0; it < ITERS; ++it) {
            RUNIT_STORE(0) RUNIT_STORE(1) RUNIT_STORE(2)
            __syncthreads();
            RUNIT_GATHER(0) RUNIT_GATHER(1) RUNIT_GATHER(2)
            __syncthreads();
        }
    }

    RUNIT_WRITE(0)
    RUNIT_WRITE(1)
    RUNIT_WRITE(2)
}

extern "C" void kernel_launch(void* const* d_in, const int* in_sizes, int n_in,
                              void* d_out, int out_size, void* d_ws, size_t ws_size,
                              hipStream_t stream) {
    const float* occ = (const float*)d_in[0];
    const float* as_ = (const float*)d_in[1];
    const float* ae_ = (const float*)d_in[2];
    float* out = (float*)d_out;
    float* ws  = (float*)d_ws;

    fused_kernel<<<NSPLAT + NSTREAM, FTPB, 0, stream>>>(occ, as_, ae_, ws, out);

    redist_kernel<<<BB, RTPB, 0, stream>>>(ws, as_, ae_, out);
}